// Round 5
// baseline (191.682 us; speedup 1.0000x reference)
//
#include <hip/hip_runtime.h>
#include <math.h>

namespace {
constexpr int Bc = 4, Sc = 4096, Dc = 768, Gc = 64, Wc = 16, Rc = 4;
constexpr int NWc = Sc / Wc;          // 256 windows per batch row
constexpr int KEEPc = Wc - Rc;        // 12 kept tokens per window
constexpr int Ec = Wc - 1;            // 15 adjacent edges
constexpr int NQc = Dc / 4;           // 192 float4 per x row
constexpr size_t X_ELEMS = (size_t)Bc * NWc * KEEPc * Dc;
constexpr size_t S_ELEMS = (size_t)Bc * NWc * KEEPc * Sc;
constexpr int NROWS = Bc * NWc * KEEPc;                    // 12288 output rows

typedef float vf4 __attribute__((ext_vector_type(4)));
}

// ---------------- K1: selection only (GEMM g=xw@Wg, sims, greedy match) -----
// One block per window; 4 waves split K=768; lane = G-column.
// Writes: p_out, meta[row] = w | mg<<4, wts[row] = {aS, bS}.
__global__ __launch_bounds__(256, 4)
void tm_select(const float* __restrict__ x, const int* __restrict__ pos,
               const float* __restrict__ Wg, float* __restrict__ out,
               int* __restrict__ meta, float2* __restrict__ wts) {
  const int wid = blockIdx.x;          // 0..1023
  const int b = wid >> 8;
  const int n = wid & (NWc - 1);
  const int tid = threadIdx.x;
  const int lane = tid & 63;
  const int wq = tid >> 6;

  const float4* xr4 = reinterpret_cast<const float4*>(x + (size_t)(b * Sc + n * Wc) * Dc);

  float acc[Wc];
#pragma unroll
  for (int w = 0; w < Wc; ++w) acc[w] = 0.f;

  const int q0 = wq * (NQc / 4);       // 48 float4-steps per wave
  for (int q = 0; q < NQc / 4; ++q) {
    const int d4 = q0 + q;
    const int d = d4 * 4;
    const float w0 = Wg[(size_t)d * Gc + lane];
    const float w1 = Wg[(size_t)(d + 1) * Gc + lane];
    const float w2 = Wg[(size_t)(d + 2) * Gc + lane];
    const float w3 = Wg[(size_t)(d + 3) * Gc + lane];
#pragma unroll
    for (int w = 0; w < Wc; ++w) {
      const float4 xv = xr4[w * NQc + d4];               // wave-broadcast 16B
      acc[w] = fmaf(xv.x, w0, acc[w]);
      acc[w] = fmaf(xv.y, w1, acc[w]);
      acc[w] = fmaf(xv.z, w2, acc[w]);
      acc[w] = fmaf(xv.w, w3, acc[w]);
    }
  }

  __shared__ float part[4][Wc][64];    // 16 KiB
#pragma unroll
  for (int w = 0; w < Wc; ++w) part[wq][w][lane] = acc[w];
  __syncthreads();

  float red[Wc + Ec];
  {
    float g[Wc];
#pragma unroll
    for (int w = 0; w < Wc; ++w)
      g[w] = part[0][w][lane] + part[1][w][lane] + part[2][w][lane] + part[3][w][lane];
#pragma unroll
    for (int w = 0; w < Wc; ++w) red[w] = g[w] * g[w];
#pragma unroll
    for (int e = 0; e < Ec; ++e) red[Wc + e] = g[e] * g[e + 1];
  }
#pragma unroll
  for (int m = 1; m < 64; m <<= 1) {
#pragma unroll
    for (int i = 0; i < Wc + Ec; ++i) red[i] += __shfl_xor(red[i], m, 64);
  }

  float nr[Wc];
#pragma unroll
  for (int w = 0; w < Wc; ++w) nr[w] = sqrtf(red[w]);

  float sv[Ec];
#pragma unroll
  for (int e = 0; e < Ec; ++e)
    sv[e] = red[Wc + e] / (fmaxf(nr[e], 1e-12f) * fmaxf(nr[e + 1], 1e-12f));

  // greedy: 4 rounds of max-compatible-edge (== stable sorted-scan greedy)
  unsigned sel = 0, used = 0;
#pragma unroll
  for (int round = 0; round < Rc; ++round) {
    float best = -1e30f;
    int bi = 0;
#pragma unroll
    for (int e = 0; e < Ec; ++e) {
      const bool ok = ((used >> e) & 3u) == 0u;
      const float v = ok ? sv[e] : -1e30f;
      if (v > best) { best = v; bi = e; }   // strict > => smallest index wins ties
    }
    sel |= (1u << bi);
    used |= (3u << bi);
  }

  if (wq == 0 && lane < KEEPc) {
    const int k = lane;
    int w = 0, c = 0;
#pragma unroll
    for (int t = 0; t < Wc; ++t) {
      const bool kept = (t == 0) || (((sel >> (t - 1)) & 1u) == 0u);
      if (kept && c == k) w = t;
      c += kept ? 1 : 0;
    }
    const bool mg = (w < Ec) && (((sel >> w) & 1u) != 0u);
    float wi = 0.f, wj = 0.f;
#pragma unroll
    for (int t = 0; t < Wc; ++t) {
      wi = (t == w) ? nr[t] : wi;
      wj = (t == (w + 1) && w + 1 < Wc) ? nr[t] : wj;
    }
    float aS = 1.f, bS = 0.f;
    if (mg) {
      const float tot = wi + wj + 1e-8f;
      aS = wi / tot;
      bS = wj / tot;
    }
    const int row = wid * KEEPc + k;
    meta[row] = w | (mg ? 16 : 0);
    wts[row] = make_float2(aS, bS);
    const int p = pos[b * Sc + n * Wc + w];
    out[X_ELEMS + S_ELEMS + (size_t)row] = (float)p;
  }
}

// ---------------- K2: one output row per 1024-thread block, 1 f4/thread -----
// No LDS, no barriers, ~minimal VGPR -> 2 blocks/CU = 100% occupancy.
__global__ __launch_bounds__(1024)
void tm_rows(const float* __restrict__ x, const float* __restrict__ src,
             const int* __restrict__ meta, const float2* __restrict__ wts,
             float* __restrict__ out) {
  const int gid = blockIdx.x;              // 0..12287 == (b*NW + n)*KEEP + k
  const int b = gid / (NWc * KEEPc);
  const int m = gid - b * (NWc * KEEPc);
  const int n = m / KEEPc;
  const int t = threadIdx.x;

  const int mt = meta[gid];                // uniform -> scalar load
  const int w = mt & 15;
  const bool mg = (mt & 16) != 0;
  const size_t tokBase = (size_t)(b * Sc + n * Wc + w);

  // s row: exactly 1024 float4
  const vf4* s1 = reinterpret_cast<const vf4*>(src + tokBase * Sc);
  vf4 a = s1[t];
  if (mg) {
    const vf4 c = s1[t + (Sc / 4)];
    a = a + c;
  }
  __builtin_nontemporal_store(a, reinterpret_cast<vf4*>(out + X_ELEMS + (size_t)gid * Sc) + t);

  // x row: first 192 threads, 1 float4 each
  if (t < NQc) {
    const float2 ab = wts[gid];
    const vf4* xs = reinterpret_cast<const vf4*>(x + tokBase * Dc);
    const vf4 xa = xs[t];
    const vf4 xc = xs[t + (mg ? NQc : 0)];
    __builtin_nontemporal_store(ab.x * xa + ab.y * xc,
                                reinterpret_cast<vf4*>(out + (size_t)gid * Dc) + t);
  }
}

extern "C" void kernel_launch(void* const* d_in, const int* in_sizes, int n_in,
                              void* d_out, int out_size, void* d_ws, size_t ws_size,
                              hipStream_t stream) {
  const float* x = (const float*)d_in[0];
  const float* src = (const float*)d_in[1];
  const int* pos = (const int*)d_in[2];
  const float* Wg = (const float*)d_in[3];
  float* out = (float*)d_out;
  int* meta = (int*)d_ws;
  float2* wts = (float2*)((char*)d_ws + 64 * 1024);

  tm_select<<<dim3(Bc * NWc), dim3(256), 0, stream>>>(x, pos, Wg, out, meta, wts);
  tm_rows<<<dim3(NROWS), dim3(1024), 0, stream>>>(x, src, meta, wts, out);
}